// Round 1
// 559.681 us; speedup vs baseline: 1.0316x; 1.0316x over previous
//
#include <hip/hip_runtime.h>
#include <stdint.h>

// ---------- types ----------
typedef unsigned short bf16_t;
typedef __attribute__((ext_vector_type(8))) short   short8;   // 8 bf16 = 4 VGPRs (MFMA A/B frag)
typedef __attribute__((ext_vector_type(4))) float   floatx4;  // MFMA C/D frag
typedef __attribute__((ext_vector_type(4))) unsigned int   uint4v;
typedef __attribute__((ext_vector_type(4))) unsigned short ushort4v;

#define GAS __attribute__((address_space(1)))
#define LAS __attribute__((address_space(3)))

__device__ __forceinline__ unsigned short f2bf(float f) {
  unsigned u = __float_as_uint(f);
  u += 0x7FFFu + ((u >> 16) & 1u);   // RNE
  return (unsigned short)(u >> 16);
}
__device__ __forceinline__ void store_out(float* p, float v) { *p = v; }
__device__ __forceinline__ void store_out(bf16_t* p, float v) { *p = f2bf(v); }

__device__ __forceinline__ void g2l16(const bf16_t* g, bf16_t* l) {
  // async global->LDS, 16B/lane; LDS dest is wave-uniform base + lane*16
  __builtin_amdgcn_global_load_lds((const GAS uint32_t*)g, (LAS uint32_t*)l, 16, 0, 0);
}

// ---------- fp32 -> bf16 converts ----------
__global__ __launch_bounds__(256) void conv_f32_bf16(const float* __restrict__ s,
                                                     bf16_t* __restrict__ d) {
  size_t i = ((size_t)blockIdx.x * 256 + threadIdx.x) * 4;
  float4 v = *(const float4*)(s + i);
  ushort4v o = { f2bf(v.x), f2bf(v.y), f2bf(v.z), f2bf(v.w) };
  *(ushort4v*)(d + i) = o;
}

__global__ __launch_bounds__(256) void conv_w(const float* __restrict__ w0, const float* __restrict__ w1,
                                              const float* __restrict__ w2, const float* __restrict__ w3,
                                              bf16_t* __restrict__ d) {
  const float* s = blockIdx.y == 0 ? w0 : blockIdx.y == 1 ? w1 : blockIdx.y == 2 ? w2 : w3;
  size_t i = ((size_t)blockIdx.x * 256 + threadIdx.x) * 4;
  float4 v = *(const float4*)(s + i);
  ushort4v o = { f2bf(v.x), f2bf(v.y), f2bf(v.z), f2bf(v.w) };
  *(ushort4v*)(d + (size_t)blockIdx.y * 1048576 + i) = o;
}

// ---------- GEMM: C[M,N] = A[M,K] * B[N,K]^T (+bias) * scale ----------
// 256x256 tile, BK=64, 8 waves (2M x 4N), 512 threads, 128 KB LDS.
// 8-phase schedule (HK/m201 template, T2+T3+T4+T5) in plain HIP:
//   phase = (k-half, m-half) quadrant; 16 MFMA/phase; B frags reg-reused
//   across phase pairs (8/4/8/4 ds_read_b128 per phase).
// Staging unit = {A|B} x {k-half}: 16 KB = 2 x global_load_lds(16B)/thread.
// Per K-tile t:  p1 stages A(t+1).k1, p2 B(t+1).k1  (other buffer, no race)
//                p3 stages A(t+2).k0, p4 B(t+2).k0  (SAME buffer: k0 region
//                is dead after phase 2 -> provably race-free with per-phase
//                barriers keeping waves phase-locked)
// Single gate per K-tile: s_waitcnt vmcnt(4) at p4 retires exactly tile
// t+1's 4 units, leaves t+2's k0 units (4 loads) in flight. Never vmcnt(0)
// in steady state (T4 is the gain: m218 +38-73%).
// LDS swizzle (T2): within each [256 rows][32 k] region, 16B chunk slot =
// chunk ^ ((row>>1)&3); applied on the GLOBAL source address (rule 21:
// global_load_lds dest must stay linear). ds_read_b128 frag reads then land
// 2 lanes/bank per 16-lane group = conflict-free (m136: 2-way is free).
template <typename OutT>
__global__ __launch_bounds__(512, 2) void gemm256(
    const bf16_t* __restrict__ A, const bf16_t* __restrict__ B,
    const float* __restrict__ bias, OutT* __restrict__ C,
    int M, int N, int K, long aBat, long bBat, long cBat, float scale)
{
  const int tid  = threadIdx.x;
  const int lane = tid & 63;
  const int wv   = tid >> 6;

  // bijective XCD swizzle (m204, r=0 case; all launches have nwg%8==0):
  // contiguous wgid chunk per XCD -> blocks sharing an A-panel colocate.
  int bx, by, bz;
  {
    const int gx = gridDim.x, gy = gridDim.y, gz = gridDim.z;
    const int nwg = gx * gy * gz;
    int flat = (blockIdx.z * gy + blockIdx.y) * gx + blockIdx.x;
    if ((nwg & 7) == 0) {
      const int q = nwg >> 3;
      flat = (flat & 7) * q + (flat >> 3);
    }
    bx = flat % gx;
    const int rem = flat / gx;
    by = rem % gy;
    bz = rem / gy;
  }
  const int bm = by * 256;
  const int bn = bx * 256;
  A += (size_t)bz * aBat;
  B += (size_t)bz * bBat;
  C += (size_t)bz * cBat;

  __shared__ bf16_t sm[65536];   // 128 KB: A[2][2][8192] then B[2][2][8192]

  const int nt = K >> 6;

  // wave -> 128x64 C sub-tile
  const int wm = (wv >> 2) * 128;
  const int wn = (wv & 3) * 64;

  // fragment addressing: lane l reads row (base + (l&15)), k-chunk (l>>4);
  // swizzled chunk = kq ^ ((row>>1)&3) and (row>>1)&3 == (fr>>1)&3 (16-row
  // aligned frag bases) -> per-lane constant.
  const int fr = lane & 15;
  const int kq = lane >> 4;
  const int chE = kq ^ ((fr >> 1) & 3);
  const unsigned fA = (unsigned)((wm + fr) * 32 + chE * 8);
  const unsigned fB = (unsigned)((wn + fr) * 32 + chE * 8);

  // staging addressing: LDS linear chunk i = tid + j*512 -> (row=i>>2, slot=i&3);
  // global source chunk = slot ^ ((row>>1)&3) = (i&3)^((i>>3)&3) (j-invariant).
  const unsigned c0    = (unsigned)((tid & 3) ^ ((tid >> 3) & 3));
  const unsigned soff  = (unsigned)((tid >> 2) * K + c0 * 8);
  const unsigned kx128 = (unsigned)(K << 7);           // 128*K elems
  const unsigned lOff  = (unsigned)(wv * 512 + lane * 8);

  const bf16_t* gA = A + (size_t)bm * K;
  const bf16_t* gB = B + (size_t)bn * K;

#define SMA(b, kh) (sm + (((b) << 1) | (kh)) * 8192)
#define SMB(b, kh) (sm + 32768 + (((b) << 1) | (kh)) * 8192)
#define STG(gbase, lbase)                                   \
  do {                                                      \
    g2l16((gbase) + soff,         (lbase) + lOff);          \
    g2l16((gbase) + soff + kx128, (lbase) + lOff + 4096);   \
  } while (0)

  floatx4 acc[8][4];
  floatx4 zero = {0.0f, 0.0f, 0.0f, 0.0f};
#pragma unroll
  for (int i = 0; i < 8; i++)
#pragma unroll
    for (int j = 0; j < 4; j++) acc[i][j] = zero;

  // ---- prologue: tile0 fully + tile1's k0 units (steady-state invariant:
  //      entering tile t, {A,B}(t+1).k0 are the only loads in flight) ----
  STG(gA,      SMA(0, 0));
  STG(gB,      SMB(0, 0));
  STG(gA + 32, SMA(0, 1));
  STG(gB + 32, SMB(0, 1));
  if (nt > 1) {
    STG(gA + 64, SMA(1, 0));
    STG(gB + 64, SMB(1, 0));
    asm volatile("s_waitcnt vmcnt(4)" ::: "memory");
  } else {
    asm volatile("s_waitcnt vmcnt(0)" ::: "memory");
  }
  asm volatile("s_barrier" ::: "memory");

  int cur = 0;
  for (int t = 0; t < nt; ++t) {
    const int kc = t << 6;
    short8 a_[4], b_[4];
    const bf16_t* Ac0 = SMA(cur, 0);
    const bf16_t* Ac1 = SMA(cur, 1);
    const bf16_t* Bc0 = SMB(cur, 0);
    const bf16_t* Bc1 = SMB(cur, 1);

    // ===== phase 1: k0, m-half 0 | stage A(t+1).k1 -> buf^1 =====
#pragma unroll
    for (int i = 0; i < 4; i++) a_[i] = *(const short8*)(Ac0 + fA + i * 512);
#pragma unroll
    for (int i = 0; i < 4; i++) b_[i] = *(const short8*)(Bc0 + fB + i * 512);
    if (t + 1 < nt) STG(gA + kc + 96, SMA(cur ^ 1, 1));
    asm volatile("s_barrier" ::: "memory");
    __builtin_amdgcn_s_setprio(1);
#pragma unroll
    for (int mi = 0; mi < 4; mi++)
#pragma unroll
      for (int ni = 0; ni < 4; ni++)
        acc[mi][ni] = __builtin_amdgcn_mfma_f32_16x16x32_bf16(a_[mi], b_[ni], acc[mi][ni], 0, 0, 0);
    __builtin_amdgcn_s_setprio(0);
    asm volatile("s_barrier" ::: "memory");

    // ===== phase 2: k0, m-half 1 (B regs reused) | stage B(t+1).k1 =====
#pragma unroll
    for (int i = 0; i < 4; i++) a_[i] = *(const short8*)(Ac0 + fA + (4 + i) * 512);
    if (t + 1 < nt) STG(gB + kc + 96, SMB(cur ^ 1, 1));
    asm volatile("s_barrier" ::: "memory");
    __builtin_amdgcn_s_setprio(1);
#pragma unroll
    for (int mi = 0; mi < 4; mi++)
#pragma unroll
      for (int ni = 0; ni < 4; ni++)
        acc[4 + mi][ni] = __builtin_amdgcn_mfma_f32_16x16x32_bf16(a_[mi], b_[ni], acc[4 + mi][ni], 0, 0, 0);
    __builtin_amdgcn_s_setprio(0);
    asm volatile("s_barrier" ::: "memory");

    // ===== phase 3: k1, m-half 0 | stage A(t+2).k0 -> SAME buf (k0 dead) =====
#pragma unroll
    for (int i = 0; i < 4; i++) a_[i] = *(const short8*)(Ac1 + fA + i * 512);
#pragma unroll
    for (int i = 0; i < 4; i++) b_[i] = *(const short8*)(Bc1 + fB + i * 512);
    if (t + 2 < nt) STG(gA + kc + 128, SMA(cur, 0));
    asm volatile("s_barrier" ::: "memory");
    __builtin_amdgcn_s_setprio(1);
#pragma unroll
    for (int mi = 0; mi < 4; mi++)
#pragma unroll
      for (int ni = 0; ni < 4; ni++)
        acc[mi][ni] = __builtin_amdgcn_mfma_f32_16x16x32_bf16(a_[mi], b_[ni], acc[mi][ni], 0, 0, 0);
    __builtin_amdgcn_s_setprio(0);
    asm volatile("s_barrier" ::: "memory");

    // ===== phase 4: k1, m-half 1 (B reused) | stage B(t+2).k0 | GATE =====
#pragma unroll
    for (int i = 0; i < 4; i++) a_[i] = *(const short8*)(Ac1 + fA + (4 + i) * 512);
    if (t + 2 < nt) STG(gB + kc + 128, SMB(cur, 0));
    asm volatile("s_barrier" ::: "memory");
    __builtin_amdgcn_s_setprio(1);
#pragma unroll
    for (int mi = 0; mi < 4; mi++)
#pragma unroll
      for (int ni = 0; ni < 4; ni++)
        acc[4 + mi][ni] = __builtin_amdgcn_mfma_f32_16x16x32_bf16(a_[mi], b_[ni], acc[4 + mi][ni], 0, 0, 0);
    __builtin_amdgcn_s_setprio(0);
    if (t + 2 < nt) asm volatile("s_waitcnt vmcnt(4)" ::: "memory");
    else            asm volatile("s_waitcnt vmcnt(0)" ::: "memory");
    asm volatile("s_barrier" ::: "memory");

    cur ^= 1;
  }
#undef STG
#undef SMB
#undef SMA

  // epilogue: C/D layout col=lane&15, row=(lane>>4)*4+reg  [verified m89]
  const int er = (lane >> 4) * 4;
  const int ec = lane & 15;
#pragma unroll
  for (int nf = 0; nf < 4; nf++) {
    const int col = bn + wn + nf * 16 + ec;
    const float bval = bias ? bias[col] : 0.0f;
#pragma unroll
    for (int mf = 0; mf < 8; mf++) {
      const int row0 = bm + wm + mf * 16 + er;
#pragma unroll
      for (int r = 0; r < 4; r++) {
        float v = (acc[mf][nf][r] + bval) * scale;
        store_out(C + (size_t)(row0 + r) * N + col, v);
      }
    }
  }
}

// ---------- row softmax in place, bf16 [16384][2048], one block per row ----------
__global__ __launch_bounds__(256) void softmax_rows(bf16_t* __restrict__ S) {
  const int tid = threadIdx.x;
  bf16_t* row = S + (size_t)blockIdx.x * 2048;
  uint4v raw = *(const uint4v*)(row + tid * 8);
  float x[8];
#pragma unroll
  for (int j = 0; j < 4; j++) {
    unsigned w = raw[j];
    x[2 * j]     = __uint_as_float(w << 16);
    x[2 * j + 1] = __uint_as_float(w & 0xFFFF0000u);
  }
  float m = -1e30f;
#pragma unroll
  for (int j = 0; j < 8; j++) m = fmaxf(m, x[j]);
  for (int o = 32; o > 0; o >>= 1) m = fmaxf(m, __shfl_xor(m, o, 64));
  __shared__ float red[4];
  if ((tid & 63) == 0) red[tid >> 6] = m;
  __syncthreads();
  m = fmaxf(fmaxf(red[0], red[1]), fmaxf(red[2], red[3]));

  float e[8];
  float s = 0.0f;
#pragma unroll
  for (int j = 0; j < 8; j++) { e[j] = __expf(x[j] - m); s += e[j]; }
  for (int o = 32; o > 0; o >>= 1) s += __shfl_xor(s, o, 64);
  __syncthreads();
  if ((tid & 63) == 0) red[tid >> 6] = s;
  __syncthreads();
  s = red[0] + red[1] + red[2] + red[3];
  float inv = 1.0f / s;

  uint4v o4;
#pragma unroll
  for (int j = 0; j < 4; j++) {
    unsigned lo = f2bf(e[2 * j] * inv);
    unsigned hi = f2bf(e[2 * j + 1] * inv);
    o4[j] = lo | (hi << 16);
  }
  *(uint4v*)(row + tid * 8) = o4;
}

// ---------- V [b][2048][1024] -> Vt [b][1024][2048], 64x64 LDS tiles ----------
__global__ __launch_bounds__(256) void transpose64(const bf16_t* __restrict__ V,
                                                   bf16_t* __restrict__ Vt) {
  __shared__ bf16_t t[64][72];   // 72: keep 16B alignment (144B row) + conflict break
  const int tid = threadIdx.x;
  const int e0 = blockIdx.x * 64;
  const int s0 = blockIdx.y * 64;
  const size_t bb = (size_t)blockIdx.z * (2048 * 1024);
  const int r = tid >> 2;
  const int c = (tid & 3) * 16;
  const bf16_t* src = V + bb + (size_t)(s0 + r) * 1024 + e0 + c;
  uint4v v0 = *(const uint4v*)src;
  uint4v v1 = *(const uint4v*)(src + 8);
  *(uint4v*)&t[r][c]     = v0;
  *(uint4v*)&t[r][c + 8] = v1;
  __syncthreads();
  __attribute__((aligned(16))) bf16_t vals[16];
#pragma unroll
  for (int j = 0; j < 16; j++) vals[j] = t[c + j][r];
  bf16_t* dst = Vt + bb + (size_t)(e0 + r) * 2048 + s0 + c;
  *(uint4v*)dst       = *(const uint4v*)vals;
  *(uint4v*)(dst + 8) = *(const uint4v*)(vals + 8);
}

// ---------- launch ----------
extern "C" void kernel_launch(void* const* d_in, const int* in_sizes, int n_in,
                              void* d_out, int out_size, void* d_ws, size_t ws_size,
                              hipStream_t stream) {
  const float* target = (const float*)d_in[0];
  const float* source = (const float*)d_in[1];
  const float* Wq = (const float*)d_in[2];
  const float* bq = (const float*)d_in[3];
  const float* Wk = (const float*)d_in[4];
  const float* bk = (const float*)d_in[5];
  const float* Wv = (const float*)d_in[6];
  const float* bv = (const float*)d_in[7];
  const float* Wo = (const float*)d_in[8];
  const float* bo = (const float*)d_in[9];
  float* out = (float*)d_out;

  // workspace layout (200 MB total), with overlays:
  //   [0,32M)      Q bf16
  //   [32M,64M)    K bf16
  //   [64M,96M)    V^T bf16
  //   [96M,104M)   Wq/Wk/Wv/Wo bf16
  //   [104M,136M)  target bf16  } S bf16 (64M) overlays both after QKV GEMMs
  //   [136M,168M)  source bf16  }
  //   [168M,200M)  V row-major bf16; attn-out overlays after transpose
  char* ws = (char*)d_ws;
  bf16_t* Qb  = (bf16_t*)(ws + 0);
  bf16_t* Kb  = (bf16_t*)(ws + 33554432);
  bf16_t* Vt  = (bf16_t*)(ws + 67108864);
  bf16_t* Wb  = (bf16_t*)(ws + 100663296);
  bf16_t* Tb  = (bf16_t*)(ws + 109051904);
  bf16_t* Sb  = Tb;                          // 67,108,864 B spanning Tb+Srcb
  bf16_t* Srb = (bf16_t*)(ws + 142606336);
  bf16_t* Vb  = (bf16_t*)(ws + 176160768);
  bf16_t* AO  = Vb;

  // 1. converts (fp32 -> bf16)
  conv_f32_bf16<<<16384, 256, 0, stream>>>(target, Tb);
  conv_f32_bf16<<<16384, 256, 0, stream>>>(source, Srb);
  conv_w<<<dim3(1024, 4), 256, 0, stream>>>(Wq, Wk, Wv, Wo, Wb);

  // 2. projections: X @ W^T + b   (Q pre-scaled by 1/sqrt(1024))
  gemm256<<<dim3(4, 64, 1), 512, 0, stream>>>(Tb,  Wb,           bq, Qb, 16384, 1024, 1024, 0L, 0L, 0L, 0.03125f);
  gemm256<<<dim3(4, 64, 1), 512, 0, stream>>>(Srb, Wb + 1048576, bk, Kb, 16384, 1024, 1024, 0L, 0L, 0L, 1.0f);
  gemm256<<<dim3(4, 64, 1), 512, 0, stream>>>(Srb, Wb + 2097152, bv, Vb, 16384, 1024, 1024, 0L, 0L, 0L, 1.0f);

  // 3. V -> V^T per batch
  transpose64<<<dim3(16, 32, 8), 256, 0, stream>>>(Vb, Vt);

  // 4. scores S = Qs @ K^T  (per batch)
  gemm256<<<dim3(8, 8, 8), 512, 0, stream>>>(Qb, Kb, (const float*)nullptr, Sb,
      2048, 2048, 1024, (long)2048 * 1024, (long)2048 * 1024, (long)2048 * 2048, 1.0f);

  // 5. softmax rows, in place
  softmax_rows<<<16384, 256, 0, stream>>>(Sb);

  // 6. out = P @ V  == P @ (V^T)^T  (per batch)
  gemm256<<<dim3(4, 8, 8), 512, 0, stream>>>(Sb, Vt, (const float*)nullptr, AO,
      2048, 1024, 2048, (long)2048 * 2048, (long)1024 * 2048, (long)2048 * 1024, 1.0f);

  // 7. final projection: AO @ Wo^T + bo -> fp32 out
  gemm256<<<dim3(4, 64, 1), 512, 0, stream>>>(AO, Wb + 3145728, bo, out,
      16384, 1024, 1024, 0L, 0L, 0L, 1.0f);
}

// Round 2
// 502.309 us; speedup vs baseline: 1.1494x; 1.1142x over previous
//
#include <hip/hip_runtime.h>
#include <stdint.h>

// ---------- types ----------
typedef unsigned short bf16_t;
typedef __attribute__((ext_vector_type(8))) short   short8;   // 8 bf16 = 4 VGPRs (MFMA A/B frag)
typedef __attribute__((ext_vector_type(4))) float   floatx4;  // MFMA C/D frag
typedef __attribute__((ext_vector_type(4))) unsigned int   uint4v;
typedef __attribute__((ext_vector_type(4))) unsigned short ushort4v;

#define GAS __attribute__((address_space(1)))
#define LAS __attribute__((address_space(3)))

__device__ __forceinline__ unsigned short f2bf(float f) {
  unsigned u = __float_as_uint(f);
  u += 0x7FFFu + ((u >> 16) & 1u);   // RNE
  return (unsigned short)(u >> 16);
}

__device__ __forceinline__ void g2l16(const bf16_t* g, bf16_t* l) {
  // async global->LDS, 16B/lane; LDS dest is wave-uniform base + lane*16
  __builtin_amdgcn_global_load_lds((const GAS uint32_t*)g, (LAS uint32_t*)l, 16, 0, 0);
}

// ---------- fp32 -> bf16 converts ----------
__global__ __launch_bounds__(256) void conv_f32_bf16(const float* __restrict__ s,
                                                     bf16_t* __restrict__ d) {
  size_t i = ((size_t)blockIdx.x * 256 + threadIdx.x) * 4;
  float4 v = *(const float4*)(s + i);
  ushort4v o = { f2bf(v.x), f2bf(v.y), f2bf(v.z), f2bf(v.w) };
  *(ushort4v*)(d + i) = o;
}

__global__ __launch_bounds__(256) void conv_w(const float* __restrict__ w0, const float* __restrict__ w1,
                                              const float* __restrict__ w2, const float* __restrict__ w3,
                                              bf16_t* __restrict__ d) {
  const float* s = blockIdx.y == 0 ? w0 : blockIdx.y == 1 ? w1 : blockIdx.y == 2 ? w2 : w3;
  size_t i = ((size_t)blockIdx.x * 256 + threadIdx.x) * 4;
  float4 v = *(const float4*)(s + i);
  ushort4v o = { f2bf(v.x), f2bf(v.y), f2bf(v.z), f2bf(v.w) };
  *(ushort4v*)(d + (size_t)blockIdx.y * 1048576 + i) = o;
}

// ---------- GEMM: C[M,N] = A[M,K] * B[N,K]^T (+bias) * scale ----------
// 256x256 tile, BK=64, 8 waves (2M x 4N), 512 threads, 128 KB LDS.
// 8-phase counted-vmcnt schedule (unchanged from R1 — see comments there).
// R2 change: LDS-staged epilogue. The scalar 2B store epilogue caused 4.6x
// HBM write amplification (WRITE_SIZE 148 MB vs 32 MB ideal): 32B partial-line
// segments were evicted from L2 mid-assembly (32 simultaneous 128KB epilogue
// footprints = 4MB = exactly one XCD's L2). Now each wave stages its 128x64
// tile in a PRIVATE 16KB LDS region (2 passes of 64 rows) and stores full
// aligned 128B lines (16B/lane dwordx4), each line written exactly once.
template <typename OutT>
__global__ __launch_bounds__(512, 2) void gemm256(
    const bf16_t* __restrict__ A, const bf16_t* __restrict__ B,
    const float* __restrict__ bias, OutT* __restrict__ C,
    int M, int N, int K, long aBat, long bBat, long cBat, float scale)
{
  const int tid  = threadIdx.x;
  const int lane = tid & 63;
  const int wv   = tid >> 6;

  // bijective XCD swizzle (m204, r=0 case; all launches have nwg%8==0):
  // contiguous wgid chunk per XCD -> blocks sharing an A-panel colocate.
  int bx, by, bz;
  {
    const int gx = gridDim.x, gy = gridDim.y, gz = gridDim.z;
    const int nwg = gx * gy * gz;
    int flat = (blockIdx.z * gy + blockIdx.y) * gx + blockIdx.x;
    if ((nwg & 7) == 0) {
      const int q = nwg >> 3;
      flat = (flat & 7) * q + (flat >> 3);
    }
    bx = flat % gx;
    const int rem = flat / gx;
    by = rem % gy;
    bz = rem / gy;
  }
  const int bm = by * 256;
  const int bn = bx * 256;
  A += (size_t)bz * aBat;
  B += (size_t)bz * bBat;
  C += (size_t)bz * cBat;

  __shared__ bf16_t sm[65536];   // 128 KB: A[2][2][8192] then B[2][2][8192]

  const int nt = K >> 6;

  // wave -> 128x64 C sub-tile
  const int wm = (wv >> 2) * 128;
  const int wn = (wv & 3) * 64;

  // fragment addressing: lane l reads row (base + (l&15)), k-chunk (l>>4);
  // swizzled chunk = kq ^ ((row>>1)&3) and (row>>1)&3 == (fr>>1)&3 (16-row
  // aligned frag bases) -> per-lane constant.
  const int fr = lane & 15;
  const int kq = lane >> 4;
  const int chE = kq ^ ((fr >> 1) & 3);
  const unsigned fA = (unsigned)((wm + fr) * 32 + chE * 8);
  const unsigned fB = (unsigned)((wn + fr) * 32 + chE * 8);

  // staging addressing: LDS linear chunk i = tid + j*512 -> (row=i>>2, slot=i&3);
  // global source chunk = slot ^ ((row>>1)&3) = (i&3)^((i>>3)&3) (j-invariant).
  const unsigned c0    = (unsigned)((tid & 3) ^ ((tid >> 3) & 3));
  const unsigned soff  = (unsigned)((tid >> 2) * K + c0 * 8);
  const unsigned kx128 = (unsigned)(K << 7);           // 128*K elems
  const unsigned lOff  = (unsigned)(wv * 512 + lane * 8);

  const bf16_t* gA = A + (size_t)bm * K;
  const bf16_t* gB = B + (size_t)bn * K;

#define SMA(b, kh) (sm + (((b) << 1) | (kh)) * 8192)
#define SMB(b, kh) (sm + 32768 + (((b) << 1) | (kh)) * 8192)
#define STG(gbase, lbase)                                   \
  do {                                                      \
    g2l16((gbase) + soff,         (lbase) + lOff);          \
    g2l16((gbase) + soff + kx128, (lbase) + lOff + 4096);   \
  } while (0)

  floatx4 acc[8][4];
  floatx4 zero = {0.0f, 0.0f, 0.0f, 0.0f};
#pragma unroll
  for (int i = 0; i < 8; i++)
#pragma unroll
    for (int j = 0; j < 4; j++) acc[i][j] = zero;

  // ---- prologue: tile0 fully + tile1's k0 units (steady-state invariant:
  //      entering tile t, {A,B}(t+1).k0 are the only loads in flight) ----
  STG(gA,      SMA(0, 0));
  STG(gB,      SMB(0, 0));
  STG(gA + 32, SMA(0, 1));
  STG(gB + 32, SMB(0, 1));
  if (nt > 1) {
    STG(gA + 64, SMA(1, 0));
    STG(gB + 64, SMB(1, 0));
    asm volatile("s_waitcnt vmcnt(4)" ::: "memory");
  } else {
    asm volatile("s_waitcnt vmcnt(0)" ::: "memory");
  }
  asm volatile("s_barrier" ::: "memory");

  int cur = 0;
  for (int t = 0; t < nt; ++t) {
    const int kc = t << 6;
    short8 a_[4], b_[4];
    const bf16_t* Ac0 = SMA(cur, 0);
    const bf16_t* Ac1 = SMA(cur, 1);
    const bf16_t* Bc0 = SMB(cur, 0);
    const bf16_t* Bc1 = SMB(cur, 1);

    // ===== phase 1: k0, m-half 0 | stage A(t+1).k1 -> buf^1 =====
#pragma unroll
    for (int i = 0; i < 4; i++) a_[i] = *(const short8*)(Ac0 + fA + i * 512);
#pragma unroll
    for (int i = 0; i < 4; i++) b_[i] = *(const short8*)(Bc0 + fB + i * 512);
    if (t + 1 < nt) STG(gA + kc + 96, SMA(cur ^ 1, 1));
    asm volatile("s_barrier" ::: "memory");
    __builtin_amdgcn_s_setprio(1);
#pragma unroll
    for (int mi = 0; mi < 4; mi++)
#pragma unroll
      for (int ni = 0; ni < 4; ni++)
        acc[mi][ni] = __builtin_amdgcn_mfma_f32_16x16x32_bf16(a_[mi], b_[ni], acc[mi][ni], 0, 0, 0);
    __builtin_amdgcn_s_setprio(0);
    asm volatile("s_barrier" ::: "memory");

    // ===== phase 2: k0, m-half 1 (B regs reused) | stage B(t+1).k1 =====
#pragma unroll
    for (int i = 0; i < 4; i++) a_[i] = *(const short8*)(Ac0 + fA + (4 + i) * 512);
    if (t + 1 < nt) STG(gB + kc + 96, SMB(cur ^ 1, 1));
    asm volatile("s_barrier" ::: "memory");
    __builtin_amdgcn_s_setprio(1);
#pragma unroll
    for (int mi = 0; mi < 4; mi++)
#pragma unroll
      for (int ni = 0; ni < 4; ni++)
        acc[4 + mi][ni] = __builtin_amdgcn_mfma_f32_16x16x32_bf16(a_[mi], b_[ni], acc[4 + mi][ni], 0, 0, 0);
    __builtin_amdgcn_s_setprio(0);
    asm volatile("s_barrier" ::: "memory");

    // ===== phase 3: k1, m-half 0 | stage A(t+2).k0 -> SAME buf (k0 dead) =====
#pragma unroll
    for (int i = 0; i < 4; i++) a_[i] = *(const short8*)(Ac1 + fA + i * 512);
#pragma unroll
    for (int i = 0; i < 4; i++) b_[i] = *(const short8*)(Bc1 + fB + i * 512);
    if (t + 2 < nt) STG(gA + kc + 128, SMA(cur, 0));
    asm volatile("s_barrier" ::: "memory");
    __builtin_amdgcn_s_setprio(1);
#pragma unroll
    for (int mi = 0; mi < 4; mi++)
#pragma unroll
      for (int ni = 0; ni < 4; ni++)
        acc[mi][ni] = __builtin_amdgcn_mfma_f32_16x16x32_bf16(a_[mi], b_[ni], acc[mi][ni], 0, 0, 0);
    __builtin_amdgcn_s_setprio(0);
    asm volatile("s_barrier" ::: "memory");

    // ===== phase 4: k1, m-half 1 (B reused) | stage B(t+2).k0 | GATE =====
#pragma unroll
    for (int i = 0; i < 4; i++) a_[i] = *(const short8*)(Ac1 + fA + (4 + i) * 512);
    if (t + 2 < nt) STG(gB + kc + 128, SMB(cur, 0));
    asm volatile("s_barrier" ::: "memory");
    __builtin_amdgcn_s_setprio(1);
#pragma unroll
    for (int mi = 0; mi < 4; mi++)
#pragma unroll
      for (int ni = 0; ni < 4; ni++)
        acc[4 + mi][ni] = __builtin_amdgcn_mfma_f32_16x16x32_bf16(a_[mi], b_[ni], acc[4 + mi][ni], 0, 0, 0);
    __builtin_amdgcn_s_setprio(0);
    if (t + 2 < nt) asm volatile("s_waitcnt vmcnt(4)" ::: "memory");
    else            asm volatile("s_waitcnt vmcnt(0)" ::: "memory");
    asm volatile("s_barrier" ::: "memory");

    cur ^= 1;
  }
#undef STG
#undef SMB
#undef SMA

  // ---- epilogue: LDS-staged, full-line stores ----
  // After the loop all global_load_lds are drained (t=nt-2 gate is vmcnt(0))
  // and every wave's last ds_read precedes its last MFMA precedes the final
  // barrier -> sm is dead. __syncthreads for safety, then each wave uses a
  // PRIVATE 16KB region (no further barriers needed).
  __syncthreads();
  {
    const int er = (lane >> 4) * 4;
    const int ec = lane & 15;
    char* wreg = (char*)sm + wv * 16384;   // per-wave private staging
#pragma unroll
    for (int pass = 0; pass < 2; ++pass) {
      // 1) deposit 64 rows x 64 cols (rows wm+pass*64 ..) with bias+scale
#pragma unroll
      for (int nf = 0; nf < 4; nf++) {
        const int lcol = nf * 16 + ec;                 // 0..63
        const float bval = bias ? bias[bn + wn + lcol] : 0.0f;
#pragma unroll
        for (int mh = 0; mh < 4; mh++) {
#pragma unroll
          for (int r = 0; r < 4; r++) {
            float v = (acc[pass * 4 + mh][nf][r] + bval) * scale;
            const int row = mh * 16 + er + r;          // 0..63
            if constexpr (sizeof(OutT) == 4) {
              ((float*)wreg)[row * 64 + lcol] = v;
            } else {
              ((bf16_t*)wreg)[row * 64 + lcol] = f2bf(v);
            }
          }
        }
      }
      // 2) read back 16B/lane along rows; store full aligned 128B lines
      const size_t rbase = (size_t)(bm + wm + pass * 64);
      if constexpr (sizeof(OutT) == 4) {
        const float* tf = (const float*)wreg;          // 64 x 256B rows
        float* Cf = (float*)C;
#pragma unroll
        for (int i = 0; i < 16; i++) {
          const int rr = i * 4 + (lane >> 4);
          floatx4 v = *(const floatx4*)(tf + rr * 64 + (lane & 15) * 4);
          *(floatx4*)(Cf + (rbase + rr) * N + bn + wn + (lane & 15) * 4) = v;
        }
      } else {
        const bf16_t* tb = (const bf16_t*)wreg;        // 64 x 128B rows
        bf16_t* Cb = (bf16_t*)C;
#pragma unroll
        for (int i = 0; i < 8; i++) {
          const int rr = i * 8 + (lane >> 3);
          short8 v = *(const short8*)(tb + rr * 64 + (lane & 7) * 8);
          *(short8*)(Cb + (rbase + rr) * N + bn + wn + (lane & 7) * 8) = v;
        }
      }
    }
  }
}

// ---------- row softmax in place, bf16 [16384][2048], one block per row ----------
__global__ __launch_bounds__(256) void softmax_rows(bf16_t* __restrict__ S) {
  const int tid = threadIdx.x;
  bf16_t* row = S + (size_t)blockIdx.x * 2048;
  uint4v raw = *(const uint4v*)(row + tid * 8);
  float x[8];
#pragma unroll
  for (int j = 0; j < 4; j++) {
    unsigned w = raw[j];
    x[2 * j]     = __uint_as_float(w << 16);
    x[2 * j + 1] = __uint_as_float(w & 0xFFFF0000u);
  }
  float m = -1e30f;
#pragma unroll
  for (int j = 0; j < 8; j++) m = fmaxf(m, x[j]);
  for (int o = 32; o > 0; o >>= 1) m = fmaxf(m, __shfl_xor(m, o, 64));
  __shared__ float red[4];
  if ((tid & 63) == 0) red[tid >> 6] = m;
  __syncthreads();
  m = fmaxf(fmaxf(red[0], red[1]), fmaxf(red[2], red[3]));

  float e[8];
  float s = 0.0f;
#pragma unroll
  for (int j = 0; j < 8; j++) { e[j] = __expf(x[j] - m); s += e[j]; }
  for (int o = 32; o > 0; o >>= 1) s += __shfl_xor(s, o, 64);
  __syncthreads();
  if ((tid & 63) == 0) red[tid >> 6] = s;
  __syncthreads();
  s = red[0] + red[1] + red[2] + red[3];
  float inv = 1.0f / s;

  uint4v o4;
#pragma unroll
  for (int j = 0; j < 4; j++) {
    unsigned lo = f2bf(e[2 * j] * inv);
    unsigned hi = f2bf(e[2 * j + 1] * inv);
    o4[j] = lo | (hi << 16);
  }
  *(uint4v*)(row + tid * 8) = o4;
}

// ---------- V [b][2048][1024] -> Vt [b][1024][2048], 64x64 LDS tiles ----------
__global__ __launch_bounds__(256) void transpose64(const bf16_t* __restrict__ V,
                                                   bf16_t* __restrict__ Vt) {
  __shared__ bf16_t t[64][72];   // 72: keep 16B alignment (144B row) + conflict break
  const int tid = threadIdx.x;
  const int e0 = blockIdx.x * 64;
  const int s0 = blockIdx.y * 64;
  const size_t bb = (size_t)blockIdx.z * (2048 * 1024);
  const int r = tid >> 2;
  const int c = (tid & 3) * 16;
  const bf16_t* src = V + bb + (size_t)(s0 + r) * 1024 + e0 + c;
  uint4v v0 = *(const uint4v*)src;
  uint4v v1 = *(const uint4v*)(src + 8);
  *(uint4v*)&t[r][c]     = v0;
  *(uint4v*)&t[r][c + 8] = v1;
  __syncthreads();
  __attribute__((aligned(16))) bf16_t vals[16];
#pragma unroll
  for (int j = 0; j < 16; j++) vals[j] = t[c + j][r];
  bf16_t* dst = Vt + bb + (size_t)(e0 + r) * 2048 + s0 + c;
  *(uint4v*)dst       = *(const uint4v*)vals;
  *(uint4v*)(dst + 8) = *(const uint4v*)(vals + 8);
}

// ---------- launch ----------
extern "C" void kernel_launch(void* const* d_in, const int* in_sizes, int n_in,
                              void* d_out, int out_size, void* d_ws, size_t ws_size,
                              hipStream_t stream) {
  const float* target = (const float*)d_in[0];
  const float* source = (const float*)d_in[1];
  const float* Wq = (const float*)d_in[2];
  const float* bq = (const float*)d_in[3];
  const float* Wk = (const float*)d_in[4];
  const float* bk = (const float*)d_in[5];
  const float* Wv = (const float*)d_in[6];
  const float* bv = (const float*)d_in[7];
  const float* Wo = (const float*)d_in[8];
  const float* bo = (const float*)d_in[9];
  float* out = (float*)d_out;

  // workspace layout (200 MB total), with overlays:
  //   [0,32M)      Q bf16
  //   [32M,64M)    K bf16
  //   [64M,96M)    V^T bf16
  //   [96M,104M)   Wq/Wk/Wv/Wo bf16
  //   [104M,136M)  target bf16  } S bf16 (64M) overlays both after QKV GEMMs
  //   [136M,168M)  source bf16  }
  //   [168M,200M)  V row-major bf16; attn-out overlays after transpose
  char* ws = (char*)d_ws;
  bf16_t* Qb  = (bf16_t*)(ws + 0);
  bf16_t* Kb  = (bf16_t*)(ws + 33554432);
  bf16_t* Vt  = (bf16_t*)(ws + 67108864);
  bf16_t* Wb  = (bf16_t*)(ws + 100663296);
  bf16_t* Tb  = (bf16_t*)(ws + 109051904);
  bf16_t* Sb  = Tb;                          // 67,108,864 B spanning Tb+Srcb
  bf16_t* Srb = (bf16_t*)(ws + 142606336);
  bf16_t* Vb  = (bf16_t*)(ws + 176160768);
  bf16_t* AO  = Vb;

  // 1. converts (fp32 -> bf16)
  conv_f32_bf16<<<16384, 256, 0, stream>>>(target, Tb);
  conv_f32_bf16<<<16384, 256, 0, stream>>>(source, Srb);
  conv_w<<<dim3(1024, 4), 256, 0, stream>>>(Wq, Wk, Wv, Wo, Wb);

  // 2. projections: X @ W^T + b   (Q pre-scaled by 1/sqrt(1024))
  gemm256<<<dim3(4, 64, 1), 512, 0, stream>>>(Tb,  Wb,           bq, Qb, 16384, 1024, 1024, 0L, 0L, 0L, 0.03125f);
  gemm256<<<dim3(4, 64, 1), 512, 0, stream>>>(Srb, Wb + 1048576, bk, Kb, 16384, 1024, 1024, 0L, 0L, 0L, 1.0f);
  gemm256<<<dim3(4, 64, 1), 512, 0, stream>>>(Srb, Wb + 2097152, bv, Vb, 16384, 1024, 1024, 0L, 0L, 0L, 1.0f);

  // 3. V -> V^T per batch
  transpose64<<<dim3(16, 32, 8), 256, 0, stream>>>(Vb, Vt);

  // 4. scores S = Qs @ K^T  (per batch)
  gemm256<<<dim3(8, 8, 8), 512, 0, stream>>>(Qb, Kb, (const float*)nullptr, Sb,
      2048, 2048, 1024, (long)2048 * 1024, (long)2048 * 1024, (long)2048 * 2048, 1.0f);

  // 5. softmax rows, in place
  softmax_rows<<<16384, 256, 0, stream>>>(Sb);

  // 6. out = P @ V  == P @ (V^T)^T  (per batch)
  gemm256<<<dim3(4, 8, 8), 512, 0, stream>>>(Sb, Vt, (const float*)nullptr, AO,
      2048, 1024, 2048, (long)2048 * 2048, (long)1024 * 2048, (long)2048 * 1024, 1.0f);

  // 7. final projection: AO @ Wo^T + bo -> fp32 out
  gemm256<<<dim3(4, 64, 1), 512, 0, stream>>>(AO, Wb + 3145728, bo, out,
      16384, 1024, 1024, 0L, 0L, 0L, 1.0f);
}